// Round 1
// baseline (633.251 us; speedup 1.0000x reference)
//
#include <hip/hip_runtime.h>

#define B_  64
#define K_  256
#define T_  64
#define DF_ 768
#define N_  1024

// ---------------------------------------------------------------------------
// K1: v[b,k,n] = sum_d f[b,d,n] * W[d,k] + bias[k]
// grid (N/128, K/128, B), block 256, 8x8 per thread, BK=16
// ---------------------------------------------------------------------------
__global__ __launch_bounds__(256) void gemm_v(const float* __restrict__ f,
                                              const float* __restrict__ W,
                                              const float* __restrict__ bias,
                                              float* __restrict__ v) {
    __shared__ float As[16][128];  // [d][k]
    __shared__ float Bs[16][128];  // [d][n]
    const int n0 = blockIdx.x * 128;
    const int k0 = blockIdx.y * 128;
    const int b  = blockIdx.z;
    const int t  = threadIdx.x;
    const int tx = t & 15, ty = t >> 4;

    const float* fb = f + (size_t)b * DF_ * N_;

    float acc[8][8];
#pragma unroll
    for (int i = 0; i < 8; i++)
#pragma unroll
        for (int j = 0; j < 8; j++) acc[i][j] = 0.f;

    for (int d0 = 0; d0 < DF_; d0 += 16) {
#pragma unroll
        for (int l = 0; l < 2; l++) {
            int q   = t + l * 256;        // [0,512)
            int row = q >> 5;             // 16 rows, 32 float4 per row
            int c4  = q & 31;
            float4 av = *(const float4*)(W  + (size_t)(d0 + row) * K_ + k0 + c4 * 4);
            *(float4*)(&As[row][c4 * 4]) = av;
            float4 bv = *(const float4*)(fb + (size_t)(d0 + row) * N_ + n0 + c4 * 4);
            *(float4*)(&Bs[row][c4 * 4]) = bv;
        }
        __syncthreads();
#pragma unroll
        for (int dd = 0; dd < 16; dd++) {
            float a[8], bb[8];
            *(float4*)&a[0]  = *(const float4*)&As[dd][ty * 4];
            *(float4*)&a[4]  = *(const float4*)&As[dd][64 + ty * 4];
            *(float4*)&bb[0] = *(const float4*)&Bs[dd][tx * 4];
            *(float4*)&bb[4] = *(const float4*)&Bs[dd][64 + tx * 4];
#pragma unroll
            for (int i = 0; i < 8; i++)
#pragma unroll
                for (int j = 0; j < 8; j++) acc[i][j] += a[i] * bb[j];
        }
        __syncthreads();
    }

    float* vb = v + (size_t)b * K_ * N_;
#pragma unroll
    for (int i = 0; i < 8; i++) {
        int k = k0 + (i < 4 ? ty * 4 + i : 64 + ty * 4 + (i - 4));
        float bk = bias[k];
        float4 o0 = make_float4(acc[i][0] + bk, acc[i][1] + bk, acc[i][2] + bk, acc[i][3] + bk);
        float4 o1 = make_float4(acc[i][4] + bk, acc[i][5] + bk, acc[i][6] + bk, acc[i][7] + bk);
        *(float4*)(vb + (size_t)k * N_ + n0 + tx * 4)      = o0;
        *(float4*)(vb + (size_t)k * N_ + n0 + 64 + tx * 4) = o1;
    }
}

// ---------------------------------------------------------------------------
// K2: s[b,t,n] = sum_k e[b,k,t] * v[b,k,n]
// grid (N/64, B), block 256, 4x4 per thread, BK=16
// ---------------------------------------------------------------------------
__global__ __launch_bounds__(256) void gemm_s(const float* __restrict__ e,
                                              const float* __restrict__ v,
                                              float* __restrict__ s) {
    __shared__ float Es[16][64];  // [k][t]
    __shared__ float Vs[16][64];  // [k][n]
    const int n0 = blockIdx.x * 64;
    const int b  = blockIdx.y;
    const int t  = threadIdx.x;
    const int tx = t & 15, ty = t >> 4;
    const float* eb = e + (size_t)b * K_ * T_;
    const float* vb = v + (size_t)b * K_ * N_;

    float acc[4][4];
#pragma unroll
    for (int i = 0; i < 4; i++)
#pragma unroll
        for (int j = 0; j < 4; j++) acc[i][j] = 0.f;

    for (int k0 = 0; k0 < K_; k0 += 16) {
        int row = t >> 4;   // 16 rows
        int c4  = t & 15;   // 16 float4 per row
        *(float4*)(&Es[row][c4 * 4]) = *(const float4*)(eb + (size_t)(k0 + row) * T_ + c4 * 4);
        *(float4*)(&Vs[row][c4 * 4]) = *(const float4*)(vb + (size_t)(k0 + row) * N_ + n0 + c4 * 4);
        __syncthreads();
#pragma unroll
        for (int dd = 0; dd < 16; dd++) {
            float a[4], bb[4];
            *(float4*)&a[0]  = *(const float4*)&Es[dd][ty * 4];
            *(float4*)&bb[0] = *(const float4*)&Vs[dd][tx * 4];
#pragma unroll
            for (int i = 0; i < 4; i++)
#pragma unroll
                for (int j = 0; j < 4; j++) acc[i][j] += a[i] * bb[j];
        }
        __syncthreads();
    }

    float* sb = s + (size_t)b * T_ * N_;
#pragma unroll
    for (int i = 0; i < 4; i++) {
        int tt = ty * 4 + i;
        float4 o = make_float4(acc[i][0], acc[i][1], acc[i][2], acc[i][3]);
        *(float4*)(sb + (size_t)tt * N_ + n0 + tx * 4) = o;
    }
}

// ---------------------------------------------------------------------------
// K3: in-place alpha = softmax(gamma*s) over n. grid B*T, block 256 (4 waves)
// ---------------------------------------------------------------------------
__global__ __launch_bounds__(256) void softmax_k(float* __restrict__ s,
                                                 const float* __restrict__ gptr) {
    const float g = gptr[0];
    float* row = s + (size_t)blockIdx.x * N_;
    const int t = threadIdx.x;

    float4 x = *(const float4*)(row + t * 4);
    x.x *= g; x.y *= g; x.z *= g; x.w *= g;

    float m = fmaxf(fmaxf(x.x, x.y), fmaxf(x.z, x.w));
#pragma unroll
    for (int off = 32; off > 0; off >>= 1) m = fmaxf(m, __shfl_xor(m, off, 64));
    __shared__ float sm[4];
    __shared__ float ss[4];
    int wave = t >> 6;
    if ((t & 63) == 0) sm[wave] = m;
    __syncthreads();
    m = fmaxf(fmaxf(sm[0], sm[1]), fmaxf(sm[2], sm[3]));

    float e0 = __expf(x.x - m), e1 = __expf(x.y - m);
    float e2 = __expf(x.z - m), e3 = __expf(x.w - m);
    float sum = e0 + e1 + e2 + e3;
#pragma unroll
    for (int off = 32; off > 0; off >>= 1) sum += __shfl_xor(sum, off, 64);
    if ((t & 63) == 0) ss[wave] = sum;
    __syncthreads();
    sum = ss[0] + ss[1] + ss[2] + ss[3];
    float inv = 1.f / sum;
    *(float4*)(row + t * 4) = make_float4(e0 * inv, e1 * inv, e2 * inv, e3 * inv);
}

// ---------------------------------------------------------------------------
// K4: c[b,k,t] = sum_n v[b,k,n] * alpha[b,t,n]
// grid (K/64, B), block 256, 4x4 per thread, BN=16 (transpose tiles in LDS)
// ---------------------------------------------------------------------------
__global__ __launch_bounds__(256) void gemm_c(const float* __restrict__ v,
                                              const float* __restrict__ alpha,
                                              float* __restrict__ c) {
    __shared__ float Vs[16][68];  // [n][k]  (+4 pad: keeps 16B align, breaks conflicts)
    __shared__ float As[16][68];  // [n][t]
    const int k0 = blockIdx.x * 64;
    const int b  = blockIdx.y;
    const int t  = threadIdx.x;
    const int tx = t & 15, ty = t >> 4;
    const float* vb = v + (size_t)b * K_ * N_ + (size_t)k0 * N_;
    const float* ab = alpha + (size_t)b * T_ * N_;

    float acc[4][4];
#pragma unroll
    for (int i = 0; i < 4; i++)
#pragma unroll
        for (int j = 0; j < 4; j++) acc[i][j] = 0.f;

    for (int n0 = 0; n0 < N_; n0 += 16) {
        int row = t >> 2;  // [0,64): k (or t) index
        int c4  = t & 3;   // 4 float4 per row of 16
        float4 vv = *(const float4*)(vb + (size_t)row * N_ + n0 + c4 * 4);
        Vs[c4 * 4 + 0][row] = vv.x; Vs[c4 * 4 + 1][row] = vv.y;
        Vs[c4 * 4 + 2][row] = vv.z; Vs[c4 * 4 + 3][row] = vv.w;
        float4 av = *(const float4*)(ab + (size_t)row * N_ + n0 + c4 * 4);
        As[c4 * 4 + 0][row] = av.x; As[c4 * 4 + 1][row] = av.y;
        As[c4 * 4 + 2][row] = av.z; As[c4 * 4 + 3][row] = av.w;
        __syncthreads();
#pragma unroll
        for (int nn = 0; nn < 16; nn++) {
            float a[4], bb[4];
            *(float4*)&a[0]  = *(const float4*)&Vs[nn][ty * 4];   // stride 68 -> 16B aligned
            *(float4*)&bb[0] = *(const float4*)&As[nn][tx * 4];
#pragma unroll
            for (int i = 0; i < 4; i++)
#pragma unroll
                for (int j = 0; j < 4; j++) acc[i][j] += a[i] * bb[j];
        }
        __syncthreads();
    }

    float* cb = c + (size_t)b * K_ * T_;
#pragma unroll
    for (int i = 0; i < 4; i++) {
        int k = k0 + ty * 4 + i;
        float4 o = make_float4(acc[i][0], acc[i][1], acc[i][2], acc[i][3]);
        *(float4*)(cb + (size_t)k * T_ + tx * 4) = o;
    }
}

// ---------------------------------------------------------------------------
// K5: cos[b,i,j] = <c[:,i], e[:,j]> / (|c[:,i]| |e[:,j]|)
// grid (T, B), block 64 (one wave); norms fused into the dot loop
// ---------------------------------------------------------------------------
__global__ __launch_bounds__(64) void cos_k(const float* __restrict__ c,
                                            const float* __restrict__ e,
                                            float* __restrict__ out) {
    const int i = blockIdx.x;
    const int b = blockIdx.y;
    const int j = threadIdx.x;
    const float* cb = c + (size_t)b * K_ * T_;
    const float* eb = e + (size_t)b * K_ * T_;

    float dot = 0.f, se = 0.f, sc = 0.f;
#pragma unroll 8
    for (int k = 0; k < K_; k++) {
        float cv = cb[(size_t)k * T_ + i];  // broadcast across the wave
        float ev = eb[(size_t)k * T_ + j];  // coalesced
        dot += cv * ev;
        se  += ev * ev;
        sc  += cv * cv;
    }
    out[((size_t)b * T_ + i) * T_ + j] = dot * rsqrtf(sc * se);
}

// ---------------------------------------------------------------------------
extern "C" void kernel_launch(void* const* d_in, const int* in_sizes, int n_in,
                              void* d_out, int out_size, void* d_ws, size_t ws_size,
                              hipStream_t stream) {
    const float* e     = (const float*)d_in[0];  // [B,K,T]
    const float* f     = (const float*)d_in[1];  // [B,DF,N]
    const float* gamma = (const float*)d_in[2];  // scalar
    const float* W     = (const float*)d_in[3];  // [DF,K]
    const float* bias  = (const float*)d_in[4];  // [K]
    float* out = (float*)d_out;                  // [B,T,T]

    // workspace layout (fp32): v | s(=alpha, in-place) | c   => ~84 MB
    float* v = (float*)d_ws;                     // B*K*N
    float* s = v + (size_t)B_ * K_ * N_;         // B*T*N
    float* c = s + (size_t)B_ * T_ * N_;         // B*K*T

    gemm_v  <<<dim3(N_ / 128, K_ / 128, B_), 256, 0, stream>>>(f, W, bias, v);
    gemm_s  <<<dim3(N_ / 64, B_),            256, 0, stream>>>(e, v, s);
    softmax_k<<<dim3(B_ * T_),               256, 0, stream>>>(s, gamma);
    gemm_c  <<<dim3(K_ / 64, B_),            256, 0, stream>>>(v, s, c);
    cos_k   <<<dim3(T_, B_),                 64,  0, stream>>>(c, e, out);
}

// Round 2
// 410.492 us; speedup vs baseline: 1.5427x; 1.5427x over previous
//
#include <hip/hip_runtime.h>

#define B_  64
#define K_  256
#define T_  64
#define DF_ 768
#define N_  1024

typedef __attribute__((ext_vector_type(8))) short bf16x8;
typedef __attribute__((ext_vector_type(4))) float f32x4;

__device__ __forceinline__ unsigned short bf_rne(float x) {
    unsigned u = __float_as_uint(x);
    unsigned r = u + 0x7fffu + ((u >> 16) & 1u);
    return (unsigned short)(r >> 16);
}

// ---------------------------------------------------------------------------
// prep_w: W[d][k] fp32 -> W_hi/W_lo [d][k] bf16 (for g), WT_hi [k][d] (for c)
// ---------------------------------------------------------------------------
__global__ __launch_bounds__(256) void prep_w(const float* __restrict__ W,
                                              unsigned short* __restrict__ W_hi,
                                              unsigned short* __restrict__ W_lo,
                                              unsigned short* __restrict__ WT_hi) {
    int d = blockIdx.x, k = threadIdx.x;
    float w = W[d * K_ + k];
    unsigned u = __float_as_uint(w);
    unsigned short hs = (unsigned short)(u >> 16);            // truncation: exact hi
    float hi = __uint_as_float(u & 0xffff0000u);
    W_hi[d * K_ + k]  = hs;
    W_lo[d * K_ + k]  = bf_rne(w - hi);
    WT_hi[k * DF_ + d] = hs;
}

// ---------------------------------------------------------------------------
// prep_e: e[b][k][t] fp32 -> eT_hi/eT_lo [b][t][k] bf16
// ---------------------------------------------------------------------------
__global__ __launch_bounds__(256) void prep_e(const float* __restrict__ e,
                                              unsigned short* __restrict__ eT_hi,
                                              unsigned short* __restrict__ eT_lo) {
    int b = blockIdx.x;
    int t = threadIdx.x & 63, kq = threadIdx.x >> 6;
    const float* eb = e + (size_t)b * K_ * T_;
    unsigned short* eh = eT_hi + (size_t)b * T_ * K_;
    unsigned short* el = eT_lo + (size_t)b * T_ * K_;
    for (int i = 0; i < 64; i++) {
        int k = kq * 64 + i;
        float x = eb[k * T_ + t];                 // coalesced over t
        unsigned u = __float_as_uint(x);
        unsigned short hs = (unsigned short)(u >> 16);
        float hi = __uint_as_float(u & 0xffff0000u);
        eh[t * K_ + k] = hs;
        el[t * K_ + k] = bf_rne(x - hi);
    }
}

// ---------------------------------------------------------------------------
// gemm_g: gT[t][d] = sum_k e[k][t]*W[d][k]   (split-bf16, 3-pass MFMA)
// A = eT[t][k], B = W as B[k][d] (LDS [d][k]), D[m=t][n=d]
// grid (DF/128, B), block 256. BK=32, 8 steps. Output split to gT_hi/gT_lo.
// ---------------------------------------------------------------------------
__global__ __launch_bounds__(256, 1) void gemm_g(const unsigned short* __restrict__ eT_hi,
                                                 const unsigned short* __restrict__ eT_lo,
                                                 const unsigned short* __restrict__ W_hi,
                                                 const unsigned short* __restrict__ W_lo,
                                                 unsigned short* __restrict__ gT_hi,
                                                 unsigned short* __restrict__ gT_lo) {
    __shared__ unsigned short LeH[64 * 40], LeL[64 * 40];
    __shared__ unsigned short LwH[128 * 40], LwL[128 * 40];
    const int dblk = blockIdx.x * 128;
    const int b = blockIdx.y;
    const int tid = threadIdx.x;
    const int lane = tid & 63, w = tid >> 6, q = lane >> 4, l16 = lane & 15;

    const unsigned short* eh = eT_hi + (size_t)b * T_ * K_;
    const unsigned short* el = eT_lo + (size_t)b * T_ * K_;

    f32x4 acc[4][2];
#pragma unroll
    for (int i = 0; i < 4; i++)
#pragma unroll
        for (int j = 0; j < 2; j++) acc[i][j] = (f32x4)(0.f);

    for (int k0 = 0; k0 < K_; k0 += 32) {
        {
            int tr = tid >> 2, c8 = (tid & 3) * 8;
            *(uint4*)&LeH[tr * 40 + c8] = *(const uint4*)&eh[tr * K_ + k0 + c8];
            *(uint4*)&LeL[tr * 40 + c8] = *(const uint4*)&el[tr * K_ + k0 + c8];
#pragma unroll
            for (int l = 0; l < 2; l++) {
                int idx = tid + l * 256;
                int r = idx >> 2, cc = (idx & 3) * 8;
                *(uint4*)&LwH[r * 40 + cc] = *(const uint4*)&W_hi[(size_t)(dblk + r) * K_ + k0 + cc];
                *(uint4*)&LwL[r * 40 + cc] = *(const uint4*)&W_lo[(size_t)(dblk + r) * K_ + k0 + cc];
            }
        }
        __syncthreads();
        bf16x8 aH[4], aL[4], bH[2], bL[2];
#pragma unroll
        for (int mt = 0; mt < 4; mt++) {
            aH[mt] = *(const bf16x8*)&LeH[(mt * 16 + l16) * 40 + q * 8];
            aL[mt] = *(const bf16x8*)&LeL[(mt * 16 + l16) * 40 + q * 8];
        }
#pragma unroll
        for (int nt = 0; nt < 2; nt++) {
            int dl = w * 32 + nt * 16 + l16;
            bH[nt] = *(const bf16x8*)&LwH[dl * 40 + q * 8];
            bL[nt] = *(const bf16x8*)&LwL[dl * 40 + q * 8];
        }
#pragma unroll
        for (int mt = 0; mt < 4; mt++)
#pragma unroll
            for (int nt = 0; nt < 2; nt++) {
                acc[mt][nt] = __builtin_amdgcn_mfma_f32_16x16x32_bf16(aH[mt], bH[nt], acc[mt][nt], 0, 0, 0);
                acc[mt][nt] = __builtin_amdgcn_mfma_f32_16x16x32_bf16(aH[mt], bL[nt], acc[mt][nt], 0, 0, 0);
                acc[mt][nt] = __builtin_amdgcn_mfma_f32_16x16x32_bf16(aL[mt], bH[nt], acc[mt][nt], 0, 0, 0);
            }
        __syncthreads();
    }

    unsigned short* gh = gT_hi + (size_t)b * T_ * DF_;
    unsigned short* gl = gT_lo + (size_t)b * T_ * DF_;
#pragma unroll
    for (int mt = 0; mt < 4; mt++)
#pragma unroll
        for (int nt = 0; nt < 2; nt++)
#pragma unroll
            for (int r = 0; r < 4; r++) {
                float x = acc[mt][nt][r];
                int t = mt * 16 + q * 4 + r;
                int d = dblk + w * 32 + nt * 16 + l16;
                unsigned u = __float_as_uint(x);
                unsigned short hs = (unsigned short)(u >> 16);
                float hi = __uint_as_float(u & 0xffff0000u);
                gh[t * DF_ + d] = hs;
                gl[t * DF_ + d] = bf_rne(x - hi);
            }
}

// ---------------------------------------------------------------------------
// gemm_s: s[t][n] = sum_d g[d][t]*f[d][n]   (split-bf16, 3-pass)
// A = gT[t][d] (pre-split), B = f transposed+split on the fly into LDS [n][d].
// 1-D grid 256 blocks, XCD-swizzled so the 4 blocks sharing b land on one XCD.
// Block tile [64t x 256n], K=DF=768, BK=32, 24 steps. HBM-bound on f.
// ---------------------------------------------------------------------------
__global__ __launch_bounds__(256, 1) void gemm_s(const unsigned short* __restrict__ gT_hi,
                                                 const unsigned short* __restrict__ gT_lo,
                                                 const float* __restrict__ f,
                                                 float* __restrict__ s) {
    __shared__ unsigned short LgH[64 * 40], LgL[64 * 40];
    __shared__ unsigned LfH[256 * 20], LfL[256 * 20];   // u32 = packed bf16 pair (d, d+1)

    const int flat = blockIdx.x;                 // 256 blocks
    const int b    = (flat & 7) * 8 + (flat >> 5);
    const int nblk = ((flat >> 3) & 3) * 256;
    const int tid = threadIdx.x;
    const int lane = tid & 63, w = tid >> 6, q = lane >> 4, l16 = lane & 15;

    const unsigned short* gh = gT_hi + (size_t)b * T_ * DF_;
    const unsigned short* gl = gT_lo + (size_t)b * T_ * DF_;

    f32x4 acc[4][4];
#pragma unroll
    for (int i = 0; i < 4; i++)
#pragma unroll
        for (int j = 0; j < 4; j++) acc[i][j] = (f32x4)(0.f);

    const int dp = tid >> 4;            // 0..15 (d-pair)
    const int nb = (tid & 15) * 4;

    for (int d0 = 0; d0 < DF_; d0 += 32) {
        {
            int tr = tid >> 2, c8 = (tid & 3) * 8;
            *(uint4*)&LgH[tr * 40 + c8] = *(const uint4*)&gh[tr * DF_ + d0 + c8];
            *(uint4*)&LgL[tr * 40 + c8] = *(const uint4*)&gl[tr * DF_ + d0 + c8];
            const float* fb = f + ((size_t)b * DF_ + d0 + dp * 2) * N_ + nblk;
#pragma unroll
            for (int it = 0; it < 4; it++) {
                int n = nb + it * 64;
                float4 x = *(const float4*)&fb[n];
                float4 y = *(const float4*)&fb[N_ + n];
                const float xs[4] = {x.x, x.y, x.z, x.w};
                const float ys[4] = {y.x, y.y, y.z, y.w};
#pragma unroll
                for (int j = 0; j < 4; j++) {
                    unsigned bx = __float_as_uint(xs[j]);
                    unsigned by = __float_as_uint(ys[j]);
                    unsigned hp = (bx >> 16) | (by & 0xffff0000u);
                    float lx = xs[j] - __uint_as_float(bx & 0xffff0000u);
                    float ly = ys[j] - __uint_as_float(by & 0xffff0000u);
                    unsigned lp = (__float_as_uint(lx) >> 16) | (__float_as_uint(ly) & 0xffff0000u);
                    LfH[(n + j) * 20 + dp] = hp;
                    LfL[(n + j) * 20 + dp] = lp;
                }
            }
        }
        __syncthreads();
        bf16x8 aH[4], aL[4], bH[4], bL[4];
#pragma unroll
        for (int mt = 0; mt < 4; mt++) {
            aH[mt] = *(const bf16x8*)&LgH[(mt * 16 + l16) * 40 + q * 8];
            aL[mt] = *(const bf16x8*)&LgL[(mt * 16 + l16) * 40 + q * 8];
        }
#pragma unroll
        for (int nt = 0; nt < 4; nt++) {
            int nl = w * 64 + nt * 16 + l16;
            bH[nt] = *(const bf16x8*)&((const unsigned short*)LfH)[nl * 40 + q * 8];
            bL[nt] = *(const bf16x8*)&((const unsigned short*)LfL)[nl * 40 + q * 8];
        }
#pragma unroll
        for (int mt = 0; mt < 4; mt++)
#pragma unroll
            for (int nt = 0; nt < 4; nt++) {
                acc[mt][nt] = __builtin_amdgcn_mfma_f32_16x16x32_bf16(aH[mt], bH[nt], acc[mt][nt], 0, 0, 0);
                acc[mt][nt] = __builtin_amdgcn_mfma_f32_16x16x32_bf16(aH[mt], bL[nt], acc[mt][nt], 0, 0, 0);
                acc[mt][nt] = __builtin_amdgcn_mfma_f32_16x16x32_bf16(aL[mt], bH[nt], acc[mt][nt], 0, 0, 0);
            }
        __syncthreads();
    }

    float* sb = s + (size_t)b * T_ * N_;
#pragma unroll
    for (int mt = 0; mt < 4; mt++)
#pragma unroll
        for (int nt = 0; nt < 4; nt++)
#pragma unroll
            for (int r = 0; r < 4; r++) {
                int t = mt * 16 + q * 4 + r;
                int n = nblk + w * 64 + nt * 16 + l16;
                sb[(size_t)t * N_ + n] = acc[mt][nt][r];
            }
}

// ---------------------------------------------------------------------------
// softmax over n: alpha[row][n] = softmax(gamma*s[row][:]) as bf16
// ---------------------------------------------------------------------------
__global__ __launch_bounds__(256) void softmax_k(const float* __restrict__ s,
                                                 unsigned short* __restrict__ alpha,
                                                 const float* __restrict__ gptr) {
    const float g = gptr[0];
    const float* row = s + (size_t)blockIdx.x * N_;
    unsigned short* arow = alpha + (size_t)blockIdx.x * N_;
    const int t = threadIdx.x;

    float4 x = *(const float4*)(row + t * 4);
    x.x *= g; x.y *= g; x.z *= g; x.w *= g;

    float m = fmaxf(fmaxf(x.x, x.y), fmaxf(x.z, x.w));
#pragma unroll
    for (int off = 32; off > 0; off >>= 1) m = fmaxf(m, __shfl_xor(m, off, 64));
    __shared__ float sm[4], ss[4];
    int wave = t >> 6;
    if ((t & 63) == 0) sm[wave] = m;
    __syncthreads();
    m = fmaxf(fmaxf(sm[0], sm[1]), fmaxf(sm[2], sm[3]));

    float e0 = __expf(x.x - m), e1 = __expf(x.y - m);
    float e2 = __expf(x.z - m), e3 = __expf(x.w - m);
    float sum = e0 + e1 + e2 + e3;
#pragma unroll
    for (int off = 32; off > 0; off >>= 1) sum += __shfl_xor(sum, off, 64);
    if ((t & 63) == 0) ss[wave] = sum;
    __syncthreads();
    sum = ss[0] + ss[1] + ss[2] + ss[3];
    float inv = 1.f / sum;
    unsigned p0 = (unsigned)bf_rne(e0 * inv) | ((unsigned)bf_rne(e1 * inv) << 16);
    unsigned p1 = (unsigned)bf_rne(e2 * inv) | ((unsigned)bf_rne(e3 * inv) << 16);
    uint2 o; o.x = p0; o.y = p1;
    *(uint2*)&arow[t * 4] = o;
}

// ---------------------------------------------------------------------------
// gemm_h: hT[t][d] = sum_n f[d][n]*alpha[t][n]   (plain bf16)
// A = f (bf16-converted on the fly, natural [d][n]), B = alpha [t][n].
// grid (DF/128, B), block tile [128d x 64t], K=N=1024, BK=64. HBM-bound on f.
// ---------------------------------------------------------------------------
__global__ __launch_bounds__(256, 1) void gemm_h(const float* __restrict__ f,
                                                 const unsigned short* __restrict__ alpha,
                                                 unsigned short* __restrict__ hT) {
    __shared__ unsigned short Lf[128 * 72];
    __shared__ unsigned short La[64 * 72];
    const int dblk = blockIdx.x * 128;
    const int b = blockIdx.y;
    const int tid = threadIdx.x;
    const int lane = tid & 63, w = tid >> 6, q = lane >> 4, l16 = lane & 15;

    const float* fb = f + (size_t)b * DF_ * N_;
    const unsigned short* ab = alpha + (size_t)b * T_ * N_;

    f32x4 acc[2][4];
#pragma unroll
    for (int i = 0; i < 2; i++)
#pragma unroll
        for (int j = 0; j < 4; j++) acc[i][j] = (f32x4)(0.f);

    for (int n0 = 0; n0 < N_; n0 += 64) {
#pragma unroll
        for (int l = 0; l < 8; l++) {
            int idx = tid + l * 256;
            int r = idx >> 4, c4 = idx & 15;
            float4 x = *(const float4*)&fb[(size_t)(dblk + r) * N_ + n0 + c4 * 4];
            unsigned p0 = (unsigned)bf_rne(x.x) | ((unsigned)bf_rne(x.y) << 16);
            unsigned p1 = (unsigned)bf_rne(x.z) | ((unsigned)bf_rne(x.w) << 16);
            uint2 o; o.x = p0; o.y = p1;
            *(uint2*)&Lf[r * 72 + c4 * 4] = o;
        }
#pragma unroll
        for (int l = 0; l < 2; l++) {
            int idx = tid + l * 256;
            int r = idx >> 3, c8 = (idx & 7) * 8;
            *(uint4*)&La[r * 72 + c8] = *(const uint4*)&ab[(size_t)r * N_ + n0 + c8];
        }
        __syncthreads();
        bf16x8 af[2][2], bb[4][2];
#pragma unroll
        for (int mt = 0; mt < 2; mt++)
#pragma unroll
            for (int kk = 0; kk < 2; kk++)
                af[mt][kk] = *(const bf16x8*)&Lf[(w * 32 + mt * 16 + l16) * 72 + kk * 32 + q * 8];
#pragma unroll
        for (int nt = 0; nt < 4; nt++)
#pragma unroll
            for (int kk = 0; kk < 2; kk++)
                bb[nt][kk] = *(const bf16x8*)&La[(nt * 16 + l16) * 72 + kk * 32 + q * 8];
#pragma unroll
        for (int mt = 0; mt < 2; mt++)
#pragma unroll
            for (int nt = 0; nt < 4; nt++)
#pragma unroll
                for (int kk = 0; kk < 2; kk++)
                    acc[mt][nt] = __builtin_amdgcn_mfma_f32_16x16x32_bf16(af[mt][kk], bb[nt][kk], acc[mt][nt], 0, 0, 0);
        __syncthreads();
    }

    unsigned short* hb = hT + (size_t)b * T_ * DF_;
#pragma unroll
    for (int mt = 0; mt < 2; mt++)
#pragma unroll
        for (int nt = 0; nt < 4; nt++)
#pragma unroll
            for (int r = 0; r < 4; r++) {
                int d = dblk + w * 32 + mt * 16 + q * 4 + r;
                int t = nt * 16 + l16;
                hb[(size_t)t * DF_ + d] = bf_rne(acc[mt][nt][r]);
            }
}

// ---------------------------------------------------------------------------
// gemm_c: c[k][t] = sum_d W[d][k]*h[d][t] + bias[k]   (plain bf16)
// A = WT_hi[k][d], B = hT[t][d]. grid (K/128, B), tile [128k x 64t], BK=64.
// ---------------------------------------------------------------------------
__global__ __launch_bounds__(256, 1) void gemm_c(const unsigned short* __restrict__ WT_hi,
                                                 const unsigned short* __restrict__ hT,
                                                 const float* __restrict__ bias,
                                                 float* __restrict__ c) {
    __shared__ unsigned short LW[128 * 72];
    __shared__ unsigned short Lh[64 * 72];
    const int kblk = blockIdx.x * 128;
    const int b = blockIdx.y;
    const int tid = threadIdx.x;
    const int lane = tid & 63, w = tid >> 6, q = lane >> 4, l16 = lane & 15;

    const unsigned short* hb = hT + (size_t)b * T_ * DF_;

    f32x4 acc[2][4];
#pragma unroll
    for (int i = 0; i < 2; i++)
#pragma unroll
        for (int j = 0; j < 4; j++) acc[i][j] = (f32x4)(0.f);

    for (int d0 = 0; d0 < DF_; d0 += 64) {
#pragma unroll
        for (int l = 0; l < 4; l++) {
            int idx = tid + l * 256;
            int r = idx >> 3, c8 = (idx & 7) * 8;
            *(uint4*)&LW[r * 72 + c8] = *(const uint4*)&WT_hi[(size_t)(kblk + r) * DF_ + d0 + c8];
        }
#pragma unroll
        for (int l = 0; l < 2; l++) {
            int idx = tid + l * 256;
            int r = idx >> 3, c8 = (idx & 7) * 8;
            *(uint4*)&Lh[r * 72 + c8] = *(const uint4*)&hb[(size_t)r * DF_ + d0 + c8];
        }
        __syncthreads();
        bf16x8 aw[2][2], bh[4][2];
#pragma unroll
        for (int mt = 0; mt < 2; mt++)
#pragma unroll
            for (int kk = 0; kk < 2; kk++)
                aw[mt][kk] = *(const bf16x8*)&LW[(w * 32 + mt * 16 + l16) * 72 + kk * 32 + q * 8];
#pragma unroll
        for (int nt = 0; nt < 4; nt++)
#pragma unroll
            for (int kk = 0; kk < 2; kk++)
                bh[nt][kk] = *(const bf16x8*)&Lh[(nt * 16 + l16) * 72 + kk * 32 + q * 8];
#pragma unroll
        for (int mt = 0; mt < 2; mt++)
#pragma unroll
            for (int nt = 0; nt < 4; nt++)
#pragma unroll
                for (int kk = 0; kk < 2; kk++)
                    acc[mt][nt] = __builtin_amdgcn_mfma_f32_16x16x32_bf16(aw[mt][kk], bh[nt][kk], acc[mt][nt], 0, 0, 0);
        __syncthreads();
    }

    float* cb = c + (size_t)b * K_ * T_;
#pragma unroll
    for (int mt = 0; mt < 2; mt++)
#pragma unroll
        for (int nt = 0; nt < 4; nt++)
#pragma unroll
            for (int r = 0; r < 4; r++) {
                int k = kblk + w * 32 + mt * 16 + q * 4 + r;
                int t = nt * 16 + l16;
                cb[(size_t)k * T_ + t] = acc[mt][nt][r] + bias[k];
            }
}

// ---------------------------------------------------------------------------
// K5: cos[b,i,j] = <c[:,i], e[:,j]> / (|c[:,i]| |e[:,j]|)
// ---------------------------------------------------------------------------
__global__ __launch_bounds__(64) void cos_k(const float* __restrict__ c,
                                            const float* __restrict__ e,
                                            float* __restrict__ out) {
    const int i = blockIdx.x;
    const int b = blockIdx.y;
    const int j = threadIdx.x;
    const float* cb = c + (size_t)b * K_ * T_;
    const float* eb = e + (size_t)b * K_ * T_;

    float dot = 0.f, se = 0.f, sc = 0.f;
#pragma unroll 8
    for (int k = 0; k < K_; k++) {
        float cv = cb[(size_t)k * T_ + i];
        float ev = eb[(size_t)k * T_ + j];
        dot += cv * ev;
        se  += ev * ev;
        sc  += cv * cv;
    }
    out[((size_t)b * T_ + i) * T_ + j] = dot * rsqrtf(sc * se);
}

// ---------------------------------------------------------------------------
extern "C" void kernel_launch(void* const* d_in, const int* in_sizes, int n_in,
                              void* d_out, int out_size, void* d_ws, size_t ws_size,
                              hipStream_t stream) {
    const float* e     = (const float*)d_in[0];  // [B,K,T]
    const float* f     = (const float*)d_in[1];  // [B,DF,N]
    const float* gamma = (const float*)d_in[2];
    const float* W     = (const float*)d_in[3];  // [DF,K]
    const float* bias  = (const float*)d_in[4];  // [K]
    float* out = (float*)d_out;                  // [B,T,T]

    char* p = (char*)d_ws;
    unsigned short* W_hi  = (unsigned short*)p; p += (size_t)DF_ * K_ * 2;
    unsigned short* W_lo  = (unsigned short*)p; p += (size_t)DF_ * K_ * 2;
    unsigned short* WT_hi = (unsigned short*)p; p += (size_t)DF_ * K_ * 2;
    unsigned short* eT_hi = (unsigned short*)p; p += (size_t)B_ * T_ * K_ * 2;
    unsigned short* eT_lo = (unsigned short*)p; p += (size_t)B_ * T_ * K_ * 2;
    unsigned short* gT_hi = (unsigned short*)p; p += (size_t)B_ * T_ * DF_ * 2;
    unsigned short* gT_lo = (unsigned short*)p; p += (size_t)B_ * T_ * DF_ * 2;
    float*          s     = (float*)p;          p += (size_t)B_ * T_ * N_ * 4;
    unsigned short* alpha = (unsigned short*)p; p += (size_t)B_ * T_ * N_ * 2;
    unsigned short* hT    = (unsigned short*)p; p += (size_t)B_ * T_ * DF_ * 2;
    float*          c     = (float*)p;          p += (size_t)B_ * K_ * T_ * 4;

    prep_w  <<<dim3(DF_),          256, 0, stream>>>(W, W_hi, W_lo, WT_hi);
    prep_e  <<<dim3(B_),           256, 0, stream>>>(e, eT_hi, eT_lo);
    gemm_g  <<<dim3(DF_ / 128, B_),256, 0, stream>>>(eT_hi, eT_lo, W_hi, W_lo, gT_hi, gT_lo);
    gemm_s  <<<dim3(256),          256, 0, stream>>>(gT_hi, gT_lo, f, s);
    softmax_k<<<dim3(B_ * T_),     256, 0, stream>>>(s, alpha, gamma);
    gemm_h  <<<dim3(DF_ / 128, B_),256, 0, stream>>>(f, alpha, hT);
    gemm_c  <<<dim3(K_ / 128, B_), 256, 0, stream>>>(WT_hi, hT, bias, c);
    cos_k   <<<dim3(T_, B_),       64,  0, stream>>>(c, e, out);
}

// Round 3
// 380.984 us; speedup vs baseline: 1.6621x; 1.0775x over previous
//
#include <hip/hip_runtime.h>

#define B_  64
#define K_  256
#define T_  64
#define DF_ 768
#define N_  1024

typedef __attribute__((ext_vector_type(8))) short bf16x8;
typedef __attribute__((ext_vector_type(4))) float f32x4;

__device__ __forceinline__ unsigned short bf_rne(float x) {
    unsigned u = __float_as_uint(x);
    unsigned r = u + 0x7fffu + ((u >> 16) & 1u);
    return (unsigned short)(r >> 16);
}

// ---------------------------------------------------------------------------
// prep_we: blocks [0,768): W[d][k] -> W_hi/W_lo [d][k], WT_hi [k][d]
//          blocks [768,1024): e[b][k][t] -> eT_hi/eT_lo [b][t][k]
// ---------------------------------------------------------------------------
__global__ __launch_bounds__(256) void prep_we(const float* __restrict__ W,
                                               const float* __restrict__ e,
                                               unsigned short* __restrict__ W_hi,
                                               unsigned short* __restrict__ W_lo,
                                               unsigned short* __restrict__ WT_hi,
                                               unsigned short* __restrict__ eT_hi,
                                               unsigned short* __restrict__ eT_lo) {
    int blk = blockIdx.x;
    if (blk < DF_) {
        int d = blk, k = threadIdx.x;
        float w = W[d * K_ + k];
        unsigned u = __float_as_uint(w);
        unsigned short hs = (unsigned short)(u >> 16);  // truncation: exact hi
        float hi = __uint_as_float(u & 0xffff0000u);
        W_hi[d * K_ + k]   = hs;
        W_lo[d * K_ + k]   = bf_rne(w - hi);
        WT_hi[k * DF_ + d] = hs;
    } else {
        int q = blk - DF_;            // [0,256)
        int b = q >> 2, kq = q & 3;
        int t = threadIdx.x & 63, ko = threadIdx.x >> 6;
        const float* eb = e + (size_t)b * K_ * T_;
        unsigned short* eh = eT_hi + (size_t)b * T_ * K_;
        unsigned short* el = eT_lo + (size_t)b * T_ * K_;
#pragma unroll
        for (int i = 0; i < 16; i++) {
            int k = kq * 64 + ko * 16 + i;
            float x = eb[k * T_ + t];            // coalesced over t
            unsigned u = __float_as_uint(x);
            unsigned short hs = (unsigned short)(u >> 16);
            float hi = __uint_as_float(u & 0xffff0000u);
            eh[t * K_ + k] = hs;
            el[t * K_ + k] = bf_rne(x - hi);
        }
    }
}

// ---------------------------------------------------------------------------
// gemm_g: gT[t][d] = sum_k e[k][t]*W[d][k]   (split-bf16, 3-pass MFMA)
// grid (DF/64, B) = 768 blocks, tile [64t x 64d], BK=32.
// ---------------------------------------------------------------------------
__global__ __launch_bounds__(256, 2) void gemm_g(const unsigned short* __restrict__ eT_hi,
                                                 const unsigned short* __restrict__ eT_lo,
                                                 const unsigned short* __restrict__ W_hi,
                                                 const unsigned short* __restrict__ W_lo,
                                                 unsigned short* __restrict__ gT_hi,
                                                 unsigned short* __restrict__ gT_lo) {
    __shared__ unsigned short LeH[64 * 40], LeL[64 * 40];
    __shared__ unsigned short LwH[64 * 40], LwL[64 * 40];
    const int dblk = blockIdx.x * 64;
    const int b = blockIdx.y;
    const int tid = threadIdx.x;
    const int lane = tid & 63, w = tid >> 6, q = lane >> 4, l16 = lane & 15;

    const unsigned short* eh = eT_hi + (size_t)b * T_ * K_;
    const unsigned short* el = eT_lo + (size_t)b * T_ * K_;

    f32x4 acc[4];
#pragma unroll
    for (int i = 0; i < 4; i++) acc[i] = (f32x4)(0.f);

    const int tr = tid >> 2, c8 = (tid & 3) * 8;
    for (int k0 = 0; k0 < K_; k0 += 32) {
        *(uint4*)&LeH[tr * 40 + c8] = *(const uint4*)&eh[tr * K_ + k0 + c8];
        *(uint4*)&LeL[tr * 40 + c8] = *(const uint4*)&el[tr * K_ + k0 + c8];
        *(uint4*)&LwH[tr * 40 + c8] = *(const uint4*)&W_hi[(size_t)(dblk + tr) * K_ + k0 + c8];
        *(uint4*)&LwL[tr * 40 + c8] = *(const uint4*)&W_lo[(size_t)(dblk + tr) * K_ + k0 + c8];
        __syncthreads();
        bf16x8 aH[4], aL[4], bH, bL;
#pragma unroll
        for (int mt = 0; mt < 4; mt++) {
            aH[mt] = *(const bf16x8*)&LeH[(mt * 16 + l16) * 40 + q * 8];
            aL[mt] = *(const bf16x8*)&LeL[(mt * 16 + l16) * 40 + q * 8];
        }
        int dl = w * 16 + l16;
        bH = *(const bf16x8*)&LwH[dl * 40 + q * 8];
        bL = *(const bf16x8*)&LwL[dl * 40 + q * 8];
#pragma unroll
        for (int mt = 0; mt < 4; mt++) {
            acc[mt] = __builtin_amdgcn_mfma_f32_16x16x32_bf16(aH[mt], bH, acc[mt], 0, 0, 0);
            acc[mt] = __builtin_amdgcn_mfma_f32_16x16x32_bf16(aH[mt], bL, acc[mt], 0, 0, 0);
            acc[mt] = __builtin_amdgcn_mfma_f32_16x16x32_bf16(aL[mt], bH, acc[mt], 0, 0, 0);
        }
        __syncthreads();
    }

    unsigned short* gh = gT_hi + (size_t)b * T_ * DF_;
    unsigned short* gl = gT_lo + (size_t)b * T_ * DF_;
#pragma unroll
    for (int mt = 0; mt < 4; mt++)
#pragma unroll
        for (int r = 0; r < 4; r++) {
            float x = acc[mt][r];
            int t = mt * 16 + q * 4 + r;
            int d = dblk + w * 16 + l16;
            unsigned u = __float_as_uint(x);
            unsigned short hs = (unsigned short)(u >> 16);
            float hi = __uint_as_float(u & 0xffff0000u);
            gh[t * DF_ + d] = hs;
            gl[t * DF_ + d] = bf_rne(x - hi);
        }
}

// ---------------------------------------------------------------------------
// gemm_s: s[t][n] = sum_d g[d][t]*f[d][n]   (split-bf16, 3-pass)
// 512 blocks (XCD-swizzled: all 8 n-tiles of a given b on one XCD),
// tile [64t x 128n], BK=32, 2 blocks/CU. f transposed+split on the fly; LDS
// scatter stores lane-rotated -> 2-way (free) bank aliasing.
// ---------------------------------------------------------------------------
__global__ __launch_bounds__(256, 2) void gemm_s(const unsigned short* __restrict__ gT_hi,
                                                 const unsigned short* __restrict__ gT_lo,
                                                 const float* __restrict__ f,
                                                 float* __restrict__ s) {
    __shared__ unsigned short LgH[64 * 40], LgL[64 * 40];
    __shared__ unsigned LfH[128 * 20], LfL[128 * 20];   // u32 = packed bf16 (d,d+1)

    const int flat = blockIdx.x;                  // 512 blocks
    const int b    = (flat & 7) * 8 + ((flat >> 3) & 7);
    const int nblk = (flat >> 6) * 128;
    const int tid = threadIdx.x;
    const int lane = tid & 63, w = tid >> 6, q = lane >> 4, l16 = lane & 15;

    const unsigned short* gh = gT_hi + (size_t)b * T_ * DF_;
    const unsigned short* gl = gT_lo + (size_t)b * T_ * DF_;

    f32x4 acc[4][2];
#pragma unroll
    for (int i = 0; i < 4; i++)
#pragma unroll
        for (int j = 0; j < 2; j++) acc[i][j] = (f32x4)(0.f);

    const int dp  = tid >> 4;          // d-pair 0..15
    const int nb  = (tid & 15) * 8;    // 8 consecutive n per thread
    const int rot = tid & 7;
    const int tr = tid >> 2, c8 = (tid & 3) * 8;

    for (int d0 = 0; d0 < DF_; d0 += 32) {
        *(uint4*)&LgH[tr * 40 + c8] = *(const uint4*)&gh[tr * DF_ + d0 + c8];
        *(uint4*)&LgL[tr * 40 + c8] = *(const uint4*)&gl[tr * DF_ + d0 + c8];
        {
            const float* fp = f + ((size_t)b * DF_ + d0 + dp * 2) * N_ + nblk + nb;
            float4 x0 = *(const float4*)&fp[0];
            float4 x1 = *(const float4*)&fp[4];
            float4 y0 = *(const float4*)&fp[N_ + 0];
            float4 y1 = *(const float4*)&fp[N_ + 4];
            const float xs[8] = {x0.x, x0.y, x0.z, x0.w, x1.x, x1.y, x1.z, x1.w};
            const float ys[8] = {y0.x, y0.y, y0.z, y0.w, y1.x, y1.y, y1.z, y1.w};
#pragma unroll
            for (int jj = 0; jj < 8; jj++) {
                int j = (jj + rot) & 7;            // lane-rotated: kills bank conflicts
                unsigned bx = __float_as_uint(xs[j]);
                unsigned by = __float_as_uint(ys[j]);
                unsigned hp = (bx >> 16) | (by & 0xffff0000u);
                float lx = xs[j] - __uint_as_float(bx & 0xffff0000u);
                float ly = ys[j] - __uint_as_float(by & 0xffff0000u);
                unsigned lp = (__float_as_uint(lx) >> 16) | (__float_as_uint(ly) & 0xffff0000u);
                LfH[(nb + j) * 20 + dp] = hp;
                LfL[(nb + j) * 20 + dp] = lp;
            }
        }
        __syncthreads();
        bf16x8 aH[4], aL[4], bH[2], bL[2];
#pragma unroll
        for (int mt = 0; mt < 4; mt++) {
            aH[mt] = *(const bf16x8*)&LgH[(mt * 16 + l16) * 40 + q * 8];
            aL[mt] = *(const bf16x8*)&LgL[(mt * 16 + l16) * 40 + q * 8];
        }
#pragma unroll
        for (int nt = 0; nt < 2; nt++) {
            int nl = w * 32 + nt * 16 + l16;
            bH[nt] = *(const bf16x8*)&((const unsigned short*)LfH)[nl * 40 + q * 8];
            bL[nt] = *(const bf16x8*)&((const unsigned short*)LfL)[nl * 40 + q * 8];
        }
#pragma unroll
        for (int mt = 0; mt < 4; mt++)
#pragma unroll
            for (int nt = 0; nt < 2; nt++) {
                acc[mt][nt] = __builtin_amdgcn_mfma_f32_16x16x32_bf16(aH[mt], bH[nt], acc[mt][nt], 0, 0, 0);
                acc[mt][nt] = __builtin_amdgcn_mfma_f32_16x16x32_bf16(aH[mt], bL[nt], acc[mt][nt], 0, 0, 0);
                acc[mt][nt] = __builtin_amdgcn_mfma_f32_16x16x32_bf16(aL[mt], bH[nt], acc[mt][nt], 0, 0, 0);
            }
        __syncthreads();
    }

    float* sb = s + (size_t)b * T_ * N_;
#pragma unroll
    for (int mt = 0; mt < 4; mt++)
#pragma unroll
        for (int nt = 0; nt < 2; nt++)
#pragma unroll
            for (int r = 0; r < 4; r++) {
                int t = mt * 16 + q * 4 + r;
                int n = nblk + w * 32 + nt * 16 + l16;
                sb[(size_t)t * N_ + n] = acc[mt][nt][r];
            }
}

// ---------------------------------------------------------------------------
// softmax over n -> bf16 alpha
// ---------------------------------------------------------------------------
__global__ __launch_bounds__(256) void softmax_k(const float* __restrict__ s,
                                                 unsigned short* __restrict__ alpha,
                                                 const float* __restrict__ gptr) {
    const float g = gptr[0];
    const float* row = s + (size_t)blockIdx.x * N_;
    unsigned short* arow = alpha + (size_t)blockIdx.x * N_;
    const int t = threadIdx.x;

    float4 x = *(const float4*)(row + t * 4);
    x.x *= g; x.y *= g; x.z *= g; x.w *= g;

    float m = fmaxf(fmaxf(x.x, x.y), fmaxf(x.z, x.w));
#pragma unroll
    for (int off = 32; off > 0; off >>= 1) m = fmaxf(m, __shfl_xor(m, off, 64));
    __shared__ float sm[4], ss[4];
    int wave = t >> 6;
    if ((t & 63) == 0) sm[wave] = m;
    __syncthreads();
    m = fmaxf(fmaxf(sm[0], sm[1]), fmaxf(sm[2], sm[3]));

    float e0 = __expf(x.x - m), e1 = __expf(x.y - m);
    float e2 = __expf(x.z - m), e3 = __expf(x.w - m);
    float sum = e0 + e1 + e2 + e3;
#pragma unroll
    for (int off = 32; off > 0; off >>= 1) sum += __shfl_xor(sum, off, 64);
    if ((t & 63) == 0) ss[wave] = sum;
    __syncthreads();
    sum = ss[0] + ss[1] + ss[2] + ss[3];
    float inv = 1.f / sum;
    unsigned p0 = (unsigned)bf_rne(e0 * inv) | ((unsigned)bf_rne(e1 * inv) << 16);
    unsigned p1 = (unsigned)bf_rne(e2 * inv) | ((unsigned)bf_rne(e3 * inv) << 16);
    uint2 o; o.x = p0; o.y = p1;
    *(uint2*)&arow[t * 4] = o;
}

// ---------------------------------------------------------------------------
// gemm_h: hT[t][d] = sum_n f[d][n]*alpha[t][n]   (plain bf16)
// grid (DF/64, B) = 768 blocks, tile [64d x 64t], BK=64.
// ---------------------------------------------------------------------------
__global__ __launch_bounds__(256, 2) void gemm_h(const float* __restrict__ f,
                                                 const unsigned short* __restrict__ alpha,
                                                 unsigned short* __restrict__ hT) {
    __shared__ unsigned short Lf[64 * 72];
    __shared__ unsigned short La[64 * 72];
    const int dblk = blockIdx.x * 64;
    const int b = blockIdx.y;
    const int tid = threadIdx.x;
    const int lane = tid & 63, w = tid >> 6, q = lane >> 4, l16 = lane & 15;

    const float* fb = f + (size_t)b * DF_ * N_;
    const unsigned short* ab = alpha + (size_t)b * T_ * N_;

    f32x4 acc[4];
#pragma unroll
    for (int i = 0; i < 4; i++) acc[i] = (f32x4)(0.f);

    const int fr_ = tid >> 2, fc = tid & 3;
    for (int n0 = 0; n0 < N_; n0 += 64) {
        const float* frp = fb + (size_t)(dblk + fr_) * N_ + n0 + fc * 16;
#pragma unroll
        for (int i = 0; i < 4; i++) {
            float4 x = *(const float4*)&frp[i * 4];
            unsigned p0 = (unsigned)bf_rne(x.x) | ((unsigned)bf_rne(x.y) << 16);
            unsigned p1 = (unsigned)bf_rne(x.z) | ((unsigned)bf_rne(x.w) << 16);
            uint2 o; o.x = p0; o.y = p1;
            *(uint2*)&Lf[fr_ * 72 + fc * 16 + i * 4] = o;
        }
#pragma unroll
        for (int l = 0; l < 2; l++) {
            int idx = tid * 2 + l;
            int r = idx >> 3, c8 = (idx & 7) * 8;
            *(uint4*)&La[r * 72 + c8] = *(const uint4*)&ab[(size_t)r * N_ + n0 + c8];
        }
        __syncthreads();
        bf16x8 af[2], bb[4][2];
#pragma unroll
        for (int kk = 0; kk < 2; kk++)
            af[kk] = *(const bf16x8*)&Lf[(w * 16 + l16) * 72 + kk * 32 + q * 8];
#pragma unroll
        for (int nt = 0; nt < 4; nt++)
#pragma unroll
            for (int kk = 0; kk < 2; kk++)
                bb[nt][kk] = *(const bf16x8*)&La[(nt * 16 + l16) * 72 + kk * 32 + q * 8];
#pragma unroll
        for (int nt = 0; nt < 4; nt++)
#pragma unroll
            for (int kk = 0; kk < 2; kk++)
                acc[nt] = __builtin_amdgcn_mfma_f32_16x16x32_bf16(af[kk], bb[nt][kk], acc[nt], 0, 0, 0);
        __syncthreads();
    }

    unsigned short* hb = hT + (size_t)b * T_ * DF_;
#pragma unroll
    for (int nt = 0; nt < 4; nt++)
#pragma unroll
        for (int r = 0; r < 4; r++) {
            int d = dblk + w * 16 + q * 4 + r;
            int t = nt * 16 + l16;
            hb[(size_t)t * DF_ + d] = bf_rne(acc[nt][r]);
        }
}

// ---------------------------------------------------------------------------
// gemm_c: c[k][t] = sum_d W[d][k]*h[d][t] + bias[k]   (plain bf16)
// grid (K/64, B) = 256 blocks, tile [64k x 64t], BK=64.
// ---------------------------------------------------------------------------
__global__ __launch_bounds__(256, 2) void gemm_c(const unsigned short* __restrict__ WT_hi,
                                                 const unsigned short* __restrict__ hT,
                                                 const float* __restrict__ bias,
                                                 float* __restrict__ c) {
    __shared__ unsigned short LW[64 * 72];
    __shared__ unsigned short Lh[64 * 72];
    const int kblk = blockIdx.x * 64;
    const int b = blockIdx.y;
    const int tid = threadIdx.x;
    const int lane = tid & 63, w = tid >> 6, q = lane >> 4, l16 = lane & 15;

    const unsigned short* hb = hT + (size_t)b * T_ * DF_;

    f32x4 acc[4];
#pragma unroll
    for (int i = 0; i < 4; i++) acc[i] = (f32x4)(0.f);

    for (int d0 = 0; d0 < DF_; d0 += 64) {
#pragma unroll
        for (int l = 0; l < 2; l++) {
            int idx = tid * 2 + l;
            int r = idx >> 3, c8 = (idx & 7) * 8;
            *(uint4*)&LW[r * 72 + c8] = *(const uint4*)&WT_hi[(size_t)(kblk + r) * DF_ + d0 + c8];
            *(uint4*)&Lh[r * 72 + c8] = *(const uint4*)&hb[(size_t)r * DF_ + d0 + c8];
        }
        __syncthreads();
        bf16x8 aw[2], bh[4][2];
#pragma unroll
        for (int kk = 0; kk < 2; kk++)
            aw[kk] = *(const bf16x8*)&LW[(w * 16 + l16) * 72 + kk * 32 + q * 8];
#pragma unroll
        for (int nt = 0; nt < 4; nt++)
#pragma unroll
            for (int kk = 0; kk < 2; kk++)
                bh[nt][kk] = *(const bf16x8*)&Lh[(nt * 16 + l16) * 72 + kk * 32 + q * 8];
#pragma unroll
        for (int nt = 0; nt < 4; nt++)
#pragma unroll
            for (int kk = 0; kk < 2; kk++)
                acc[nt] = __builtin_amdgcn_mfma_f32_16x16x32_bf16(aw[kk], bh[nt][kk], acc[nt], 0, 0, 0);
        __syncthreads();
    }

    float* cb = c + (size_t)b * K_ * T_;
#pragma unroll
    for (int nt = 0; nt < 4; nt++)
#pragma unroll
        for (int r = 0; r < 4; r++) {
            int k = kblk + w * 16 + q * 4 + r;
            int t = nt * 16 + l16;
            cb[(size_t)k * T_ + t] = acc[nt][r] + bias[k];
        }
}

// ---------------------------------------------------------------------------
// cos_k: cos[b,i,j] = <c[:,i], e[:,j]> / (|c[:,i]| |e[:,j]|)
// grid (T/4, B), 256 threads: wave iq handles row i = bx*4+iq.
// ---------------------------------------------------------------------------
__global__ __launch_bounds__(256) void cos_k(const float* __restrict__ c,
                                             const float* __restrict__ e,
                                             float* __restrict__ out) {
    const int iq = threadIdx.x >> 6;
    const int i = blockIdx.x * 4 + iq;
    const int b = blockIdx.y;
    const int j = threadIdx.x & 63;
    const float* cb = c + (size_t)b * K_ * T_;
    const float* eb = e + (size_t)b * K_ * T_;

    float dot = 0.f, se = 0.f, sc = 0.f;
#pragma unroll 8
    for (int k = 0; k < K_; k++) {
        float cv = cb[(size_t)k * T_ + i];
        float ev = eb[(size_t)k * T_ + j];
        dot += cv * ev;
        se  += ev * ev;
        sc  += cv * cv;
    }
    out[((size_t)b * T_ + i) * T_ + j] = dot * rsqrtf(sc * se);
}

// ---------------------------------------------------------------------------
extern "C" void kernel_launch(void* const* d_in, const int* in_sizes, int n_in,
                              void* d_out, int out_size, void* d_ws, size_t ws_size,
                              hipStream_t stream) {
    const float* e     = (const float*)d_in[0];  // [B,K,T]
    const float* f     = (const float*)d_in[1];  // [B,DF,N]
    const float* gamma = (const float*)d_in[2];
    const float* W     = (const float*)d_in[3];  // [DF,K]
    const float* bias  = (const float*)d_in[4];  // [K]
    float* out = (float*)d_out;                  // [B,T,T]

    char* p = (char*)d_ws;
    unsigned short* W_hi  = (unsigned short*)p; p += (size_t)DF_ * K_ * 2;
    unsigned short* W_lo  = (unsigned short*)p; p += (size_t)DF_ * K_ * 2;
    unsigned short* WT_hi = (unsigned short*)p; p += (size_t)DF_ * K_ * 2;
    unsigned short* eT_hi = (unsigned short*)p; p += (size_t)B_ * T_ * K_ * 2;
    unsigned short* eT_lo = (unsigned short*)p; p += (size_t)B_ * T_ * K_ * 2;
    unsigned short* gT_hi = (unsigned short*)p; p += (size_t)B_ * T_ * DF_ * 2;
    unsigned short* gT_lo = (unsigned short*)p; p += (size_t)B_ * T_ * DF_ * 2;
    float*          s     = (float*)p;          p += (size_t)B_ * T_ * N_ * 4;
    unsigned short* alpha = (unsigned short*)p; p += (size_t)B_ * T_ * N_ * 2;
    unsigned short* hT    = (unsigned short*)p; p += (size_t)B_ * T_ * DF_ * 2;
    float*          c     = (float*)p;          p += (size_t)B_ * K_ * T_ * 4;

    prep_we <<<dim3(DF_ + 256),     256, 0, stream>>>(W, e, W_hi, W_lo, WT_hi, eT_hi, eT_lo);
    gemm_g  <<<dim3(DF_ / 64, B_),  256, 0, stream>>>(eT_hi, eT_lo, W_hi, W_lo, gT_hi, gT_lo);
    gemm_s  <<<dim3(512),           256, 0, stream>>>(gT_hi, gT_lo, f, s);
    softmax_k<<<dim3(B_ * T_),      256, 0, stream>>>(s, alpha, gamma);
    gemm_h  <<<dim3(DF_ / 64, B_),  256, 0, stream>>>(f, alpha, hT);
    gemm_c  <<<dim3(K_ / 64, B_),   256, 0, stream>>>(WT_hi, hT, bias, c);
    cos_k   <<<dim3(T_ / 4, B_),    256, 0, stream>>>(c, e, out);
}